// Round 6
// baseline (412.825 us; speedup 1.0000x reference)
//
#include <hip/hip_runtime.h>
#include <stdint.h>

// Problem constants
#define T_TOK 4096
#define D_DIM 1024
#define H_DIM 2048
#define E_EXP 8
#define K_TOP 2
#define NTK   (T_TOK * K_TOP)   // 8192 (token, slot) pairs
#define MT1 256                 // M-tile rows (both GEMMs)
#define MAXT1 48                // >= 8192/256 + 8 = 40

typedef short bf16x8 __attribute__((ext_vector_type(8)));
typedef float f32x4  __attribute__((ext_vector_type(4)));

#define MINI(a, b) ((a) < (b) ? (a) : (b))
#define MFMA_BF16 __builtin_amdgcn_mfma_f32_16x16x32_bf16

__device__ __forceinline__ unsigned short f2bf(float f) {
  unsigned u = __float_as_uint(f);
  u += 0x7fffu + ((u >> 16) & 1u);   // round-to-nearest-even
  return (unsigned short)(u >> 16);
}

// async global->LDS, 16B per lane; lds base must be wave-uniform
#define GLDS16(gp, lp)                                                        \
  __builtin_amdgcn_global_load_lds(                                           \
      (const __attribute__((address_space(1))) void*)(gp),                    \
      (__attribute__((address_space(3))) void*)(lp), 16, 0, 0)

// meta layout (ints):
// [0..7] counts, [16..23] scatter cursors, [24] n_tiles
// tiles (M=256): e [32..79], r0 [80..127], valid [128..175]
// tile_start per expert [176..183], [184] = n_tiles (tstart sentinel)

// ---- k_pre: fused cvt(x, W1) + route_count (independent work, one launch) --
#define NX8   (T_TOK * D_DIM / 8)               // 524288
#define NW18  (E_EXP * 2 * H_DIM * D_DIM / 8)   // 4194304
#define NW28  (E_EXP * D_DIM * H_DIM / 8)       // 2097152
#define PRE_CVT_BLKS ((NX8 + NW18) / 256)       // 18432
#define PRE_BLKS (PRE_CVT_BLKS + 32)

__global__ __launch_bounds__(256) void k_pre(const float* __restrict__ x,
                                             const float* __restrict__ W1,
                                             const int* __restrict__ idx,
                                             unsigned short* __restrict__ xb,
                                             unsigned short* __restrict__ W1b,
                                             int* __restrict__ meta) {
  int bid = blockIdx.x;
  int tid = threadIdx.x;
  if (bid >= PRE_CVT_BLKS) {
    // route_count: 32 blocks x 256 = 8192 pairs
    __shared__ int h[E_EXP];
    if (tid < E_EXP) h[tid] = 0;
    __syncthreads();
    int i = (bid - PRE_CVT_BLKS) * 256 + tid;
    atomicAdd(&h[idx[i] & (E_EXP - 1)], 1);
    __syncthreads();
    if (tid < E_EXP) atomicAdd(&meta[tid], h[tid]);
    return;
  }
  long gid = (long)bid * 256 + tid;
  const float* src;
  unsigned short* dst;
  long i;
  if (gid < NX8) { src = x; dst = xb; i = gid; }
  else           { src = W1; dst = W1b; i = gid - NX8; }
  float4 a = ((const float4*)src)[2 * i];
  float4 b = ((const float4*)src)[2 * i + 1];
  uint4 o;
  o.x = f2bf(a.x) | ((unsigned)f2bf(a.y) << 16);
  o.y = f2bf(a.z) | ((unsigned)f2bf(a.w) << 16);
  o.z = f2bf(b.x) | ((unsigned)f2bf(b.y) << 16);
  o.w = f2bf(b.z) | ((unsigned)f2bf(b.w) << 16);
  ((uint4*)dst)[i] = o;
}

// ---- scatter: pair scatter + (block 0) tile-table build (no plan dispatch) -
__global__ __launch_bounds__(256) void k_route_scatter(const int* __restrict__ idx,
                                                       const float* __restrict__ w,
                                                       int* __restrict__ meta,
                                                       unsigned short* __restrict__ rows,
                                                       unsigned short* __restrict__ slotpos,
                                                       float* __restrict__ wv) {
  __shared__ int h[E_EXP], base[E_EXP];
  int tid = threadIdx.x;
  if (tid < E_EXP) h[tid] = 0;
  __syncthreads();
  int i = blockIdx.x * 256 + tid;
  int e = idx[i] & (E_EXP - 1);
  int r = atomicAdd(&h[e], 1);             // block-local rank
  __syncthreads();
  if (blockIdx.x == 0 && tid == 0) {
    // build tile table from counts (counts stable: k_pre completed)
    int off = 0, nt = 0;
    for (int ee = 0; ee < E_EXP; ++ee) {
      int c = meta[ee];
      meta[176 + ee] = nt;                 // first tile of expert ee
      for (int rr = 0; rr < c; rr += MT1) {
        meta[32 + nt]  = ee;
        meta[80 + nt]  = off + rr;
        meta[128 + nt] = MINI(MT1, c - rr);
        ++nt;
      }
      off += c;
    }
    meta[24]  = nt;
    meta[184] = nt;                        // sentinel for tstart[8]
  }
  if (tid < E_EXP) {
    int off = 0;
#pragma unroll
    for (int ee = 0; ee < E_EXP; ++ee)
      if (ee < tid) off += meta[ee];
    base[tid] = off + atomicAdd(&meta[16 + tid], h[tid]);
  }
  __syncthreads();
  int p = base[e] + r;
  rows[p]    = (unsigned short)(i >> 1);   // token (K_TOP = 2)
  slotpos[i] = (unsigned short)p;
  wv[p]      = w[i];
}

// ============================================================================
// GEMM1 (fat launch): h = Xg @ W1e^T, act = f2bf(u * silu(gate) * w_row)
// Blocks [0, 1536):  R0/R4-proven body, table lookup, R0 2-D geometry
//                    (tb = bid%48, y = bid/48).
// Blocks [1536, +1024): cvt(W2) f32->bf16 (only gemm2 needs it) - hides
//                       under gemm1 compute (BW headroom).
// ============================================================================
#define G1_TILES (MAXT1 * 32)   // 1536
#define CVW2_BLK 1024
#define G1_GRID  (G1_TILES + CVW2_BLK)

__global__ __launch_bounds__(256, 2) void k_gemm1(
    const unsigned short* __restrict__ xb,   // [T][1024] bf16
    const unsigned short* __restrict__ W1b,  // [E][4096][1024] bf16
    const int* __restrict__ meta,
    const unsigned short* __restrict__ rows,
    const float* __restrict__ wv,
    unsigned short* __restrict__ act,        // [8192][2048] bf16
    const float* __restrict__ W2,            // [E][1024][2048] f32
    unsigned short* __restrict__ W2b) {      // [E][1024][2048] bf16
  int bid = blockIdx.x;
  int tid = threadIdx.x;

  if (bid >= G1_TILES) {
    // cvt W2: NW28 = 2097152 chunks over 262144 threads -> 8 each
    long g0 = (long)(bid - G1_TILES) * 256 + tid;
    for (long i = g0; i < NW28; i += (long)CVW2_BLK * 256) {
      float4 a = ((const float4*)W2)[2 * i];
      float4 b = ((const float4*)W2)[2 * i + 1];
      uint4 o;
      o.x = f2bf(a.x) | ((unsigned)f2bf(a.y) << 16);
      o.y = f2bf(a.z) | ((unsigned)f2bf(a.w) << 16);
      o.z = f2bf(b.x) | ((unsigned)f2bf(b.y) << 16);
      o.w = f2bf(b.z) | ((unsigned)f2bf(b.w) << 16);
      ((uint4*)W2b)[i] = o;
    }
    return;
  }

  int nt = meta[24];
  int tb = bid % MAXT1;                      // R0 geometry: x-fastest
  int y  = bid / MAXT1;
  if (tb >= nt) return;
  int e     = meta[32 + tb];
  int r0    = meta[80 + tb];
  int valid = meta[128 + tb];
  int n0    = y << 6;

  __shared__ unsigned short lA[256 * 64];   // 32 KB
  __shared__ unsigned short lB1[64 * 64];   //  8 KB
  __shared__ unsigned short lB2[64 * 64];   //  8 KB
  __shared__ float sw[256];

  int wave = tid >> 6, lane = tid & 63;

  sw[tid] = wv[r0 + MINI(tid, valid - 1)];

  const unsigned short* w1e = W1b + (size_t)e * (4096 * 1024);

  // staging: A = 2048 chunks over 256 threads (8 each), B strips 2 each
  const unsigned short *pA[8], *pB1[2], *pB2[2];
#pragma unroll
  for (int it = 0; it < 8; ++it) {
    int c = it * 256 + tid;
    int r = c >> 3, cc = c & 7;
    int g = cc ^ (r & 7);
    int tok = rows[r0 + MINI(r, valid - 1)];
    pA[it] = xb + (size_t)tok * 1024 + g * 8;
  }
#pragma unroll
  for (int it = 0; it < 2; ++it) {
    int c = it * 256 + tid;
    int r = c >> 3, cc = c & 7;
    int g = cc ^ (r & 7);
    pB1[it] = w1e + (size_t)(n0 + r) * 1024 + g * 8;
    pB2[it] = w1e + (size_t)(2048 + n0 + r) * 1024 + g * 8;
  }

  f32x4 zero = {0.f, 0.f, 0.f, 0.f};
  f32x4 au[4][4], ag[4][4];
#pragma unroll
  for (int i = 0; i < 4; ++i)
#pragma unroll
    for (int j = 0; j < 4; ++j) { au[i][j] = zero; ag[i][j] = zero; }

  int mb = wave * 64;
  int fr = lane & 15, q = lane >> 4;

  for (int k0 = 0; k0 < 1024; k0 += 64) {
    __syncthreads();
#pragma unroll
    for (int it = 0; it < 8; ++it)
      GLDS16(pA[it] + k0, &lA[(it * 256 + wave * 64) * 8]);
#pragma unroll
    for (int it = 0; it < 2; ++it) {
      int lb = (it * 256 + wave * 64) * 8;
      GLDS16(pB1[it] + k0, &lB1[lb]);
      GLDS16(pB2[it] + k0, &lB2[lb]);
    }
    __syncthreads();
#pragma unroll
    for (int kk = 0; kk < 2; ++kk) {
      int co = (((kk << 2) + q) ^ (fr & 7)) * 8 + fr * 64;  // swizzled read
      bf16x8 a[4];
#pragma unroll
      for (int i = 0; i < 4; ++i)
        a[i] = *(const bf16x8*)&lA[(mb + i * 16) * 64 + co];
#pragma unroll
      for (int j = 0; j < 4; ++j) {
        bf16x8 bu = *(const bf16x8*)&lB1[(j * 16) * 64 + co];
        bf16x8 bg = *(const bf16x8*)&lB2[(j * 16) * 64 + co];
#pragma unroll
        for (int i = 0; i < 4; ++i) {
          au[i][j] = MFMA_BF16(a[i], bu, au[i][j], 0, 0, 0);
          ag[i][j] = MFMA_BF16(a[i], bg, ag[i][j], 0, 0, 0);
        }
      }
    }
  }

#pragma unroll
  for (int i = 0; i < 4; ++i) {
#pragma unroll
    for (int reg = 0; reg < 4; ++reg) {
      int lm = mb + i * 16 + q * 4 + reg;
      if (lm < valid) {
        float wrow = sw[lm];
        size_t orow = (size_t)(r0 + lm) * 2048;
#pragma unroll
        for (int j = 0; j < 4; ++j) {
          float u = au[i][j][reg];
          float g = ag[i][j][reg];
          float s = g / (1.f + __expf(-g));
          act[orow + (n0 + j * 16 + fr)] = f2bf(u * s * wrow);
        }
      }
    }
  }
}

// ============================================================================
// GEMM2: y_slot = act @ W2e^T (weight pre-applied), plain f32 stores into
// y_slot[8192][1024] (aliased over W1b region, dead after gemm1). No atomics.
// Expert-XCD affinity: e = bid&7 so all blocks of expert e land on one XCD
// (bid%8 round-robin heuristic) -> W2e (4MB) L2-resident, act tiles fetched
// once per XCD. Grid 8 x (8 y x 32 ti) covers worst-case skew; inactive
// blocks exit on 2 meta reads.
// ============================================================================
#define G2_GRID (E_EXP * 8 * 32)   // 2048

__global__ __launch_bounds__(256, 2) void k_gemm2(
    const unsigned short* __restrict__ act,  // [8192][2048] bf16
    const unsigned short* __restrict__ W2b,  // [E][1024][2048] bf16
    const int* __restrict__ meta,
    float* __restrict__ y) {                 // [8192][1024] fp32 (slot rows)
  int bid = blockIdx.x;
  int e  = bid & 7;
  int s  = bid >> 3;          // 0..255
  int ti = s >> 3;            // 0..31  tile index within expert
  int yy = s & 7;             // 0..7   n-strip
  int ts  = meta[176 + e];
  int ntl = meta[177 + e] - ts;
  if (ti >= ntl) return;
  int tb    = ts + ti;
  int r0    = meta[80 + tb];
  int valid = meta[128 + tb];
  int n0    = yy << 7;

  __shared__ unsigned short lA[256 * 64];   // 32 KB
  __shared__ unsigned short lB[128 * 64];   // 16 KB

  int tid = threadIdx.x;
  int wave = tid >> 6, lane = tid & 63;

  const unsigned short* w2e = W2b + (size_t)e * (1024 * 2048);

  const unsigned short *pA[8], *pB[4];
#pragma unroll
  for (int it = 0; it < 8; ++it) {
    int c = it * 256 + tid;
    int r = c >> 3, cc = c & 7;
    int g = cc ^ (r & 7);
    pA[it] = act + (size_t)(r0 + MINI(r, valid - 1)) * 2048 + g * 8;
  }
#pragma unroll
  for (int it = 0; it < 4; ++it) {
    int c = it * 256 + tid;
    int r = c >> 3, cc = c & 7;
    int g = cc ^ (r & 7);
    pB[it] = w2e + (size_t)(n0 + r) * 2048 + g * 8;
  }

  f32x4 zero = {0.f, 0.f, 0.f, 0.f};
  f32x4 acc[4][8];
#pragma unroll
  for (int i = 0; i < 4; ++i)
#pragma unroll
    for (int j = 0; j < 8; ++j) acc[i][j] = zero;

  int mb = wave * 64;
  int fr = lane & 15, q = lane >> 4;

  for (int k0 = 0; k0 < 2048; k0 += 64) {
    __syncthreads();
#pragma unroll
    for (int it = 0; it < 8; ++it)
      GLDS16(pA[it] + k0, &lA[(it * 256 + wave * 64) * 8]);
#pragma unroll
    for (int it = 0; it < 4; ++it)
      GLDS16(pB[it] + k0, &lB[(it * 256 + wave * 64) * 8]);
    __syncthreads();
#pragma unroll
    for (int kk = 0; kk < 2; ++kk) {
      int co = (((kk << 2) + q) ^ (fr & 7)) * 8 + fr * 64;
      bf16x8 a[4];
#pragma unroll
      for (int i = 0; i < 4; ++i)
        a[i] = *(const bf16x8*)&lA[(mb + i * 16) * 64 + co];
#pragma unroll
      for (int j = 0; j < 8; ++j) {
        bf16x8 b = *(const bf16x8*)&lB[(j * 16) * 64 + co];
#pragma unroll
        for (int i = 0; i < 4; ++i)
          acc[i][j] = MFMA_BF16(a[i], b, acc[i][j], 0, 0, 0);
      }
    }
  }

#pragma unroll
  for (int i = 0; i < 4; ++i) {
#pragma unroll
    for (int reg = 0; reg < 4; ++reg) {
      int lm = mb + i * 16 + q * 4 + reg;
      if (lm < valid) {
        float* yp = y + (size_t)(r0 + lm) * 1024 + n0;
#pragma unroll
        for (int j = 0; j < 8; ++j)
          yp[j * 16 + fr] = acc[i][j][reg];
      }
    }
  }
}

// ---- combine: out[t] = y[slot0(t)] + y[slot1(t)] (plain streamed adds) ----
__global__ __launch_bounds__(256) void k_combine(
    const float* __restrict__ y,
    const unsigned short* __restrict__ slotpos,
    float* __restrict__ out) {
  int t = blockIdx.x;
  int s0 = slotpos[2 * t], s1 = slotpos[2 * t + 1];
  const float4* a = (const float4*)(y + (size_t)s0 * 1024);
  const float4* b = (const float4*)(y + (size_t)s1 * 1024);
  float4* o = (float4*)(out + (size_t)t * 1024);
  int d = threadIdx.x;                      // 256 x float4 = 1024 floats
  float4 va = a[d], vb = b[d];
  float4 vo = {va.x + vb.x, va.y + vb.y, va.z + vb.z, va.w + vb.w};
  o[d] = vo;
}

extern "C" void kernel_launch(void* const* d_in, const int* in_sizes, int n_in,
                              void* d_out, int out_size, void* d_ws, size_t ws_size,
                              hipStream_t stream) {
  const float* x  = (const float*)d_in[0];   // [T][D]
  const float* w  = (const float*)d_in[1];   // [T][K]
  const int*  idx = (const int*)d_in[2];     // [T][K]
  const float* W1 = (const float*)d_in[3];   // [E][2H][D]
  const float* W2 = (const float*)d_in[4];   // [E][D][H]
  float* out = (float*)d_out;

  char* ws = (char*)d_ws;
  unsigned short* W1b = (unsigned short*)(ws);              // 67108864 B
  float*          yslot = (float*)(ws);                     // 33554432 B (alias, after gemm1)
  unsigned short* W2b = (unsigned short*)(ws + 67108864);   // 33554432 B
  unsigned short* xb  = (unsigned short*)(ws + 100663296);  //  8388608 B
  unsigned short* act = (unsigned short*)(ws + 109051904);  // 33554432 B
  unsigned short* rows    = (unsigned short*)(ws + 142606336);  // 16384 B
  unsigned short* slotpos = (unsigned short*)(ws + 142622720);  // 16384 B
  float* wv   = (float*)(ws + 142639104);                   //    32768 B
  int*   meta = (int*)(ws + 142671872);                     //     1024 B

  hipMemsetAsync(meta, 0, 1024, stream);

  k_pre<<<PRE_BLKS, 256, 0, stream>>>(x, W1, idx, xb, W1b, meta);
  k_route_scatter<<<32, 256, 0, stream>>>(idx, w, meta, rows, slotpos, wv);

  k_gemm1<<<G1_GRID, 256, 0, stream>>>(xb, W1b, meta, rows, wv, act, W2, W2b);

  k_gemm2<<<G2_GRID, 256, 0, stream>>>(act, W2b, meta, yslot);

  k_combine<<<T_TOK, 256, 0, stream>>>(yslot, slotpos, out);
}